// Round 3
// baseline (609.094 us; speedup 1.0000x reference)
//
#include <hip/hip_runtime.h>
#include <math.h>

#define N_NODES 262144
#define N_EDGES 524288
#define NB      16
#define N_PER   16384
#define KKEEP   8192
#define DIM     128
#define NEG_SLOPE 0.01f
#define CHUNK   2048        // sort chunk size (8 chunks per graph)

// ---- output layout (floats) ----
#define X_OUT   0                     // 131072*128 = 16777216
#define X_EI    16777216              // 2*E = 1048576
#define X_EW    17825792              // E   = 524288
#define X_BATCH 18350080              // B*K = 131072

__device__ __forceinline__ unsigned long long pack_key(float sc, int localIdx) {
    unsigned int u = __float_as_uint(sc);
    u = (u & 0x80000000u) ? ~u : (u | 0x80000000u);   // order-preserving map
    unsigned int inv = ~u;                            // descending score
    return ((unsigned long long)inv << 32) | (unsigned int)localIdx;
}

// ================= K1: init =================
__global__ void k_init(float* deg, int* count, int* mapping, const float* pw, float* normPw) {
    int n = blockIdx.x * 256 + threadIdx.x;
    if (n < N_NODES) { deg[n] = 1.0f; count[n] = 0; mapping[n] = -1; }
    if (n == 0) {
        float s = 0.f;
        for (int i = 0; i < DIM; i++) s += pw[i] * pw[i];
        normPw[0] = sqrtf(s);
    }
}

// ================= K2: degree + in-edge counts =================
__global__ void k_deg(const int* col, const float* w, float* deg, int* count) {
    int e = blockIdx.x * 256 + threadIdx.x;
    if (e >= N_EDGES) return;
    int c = col[e];
    atomicAdd(&deg[c], w[e]);
    atomicAdd(&count[c], 1);
}

// ================= K3a: per-block exclusive scan (2048/block) =================
__global__ void k_scan1(const int* count, int* offs, int* blockSums) {
    __shared__ int s[2048];
    int base = blockIdx.x * 2048;
    int t = threadIdx.x;  // 1024 threads
    s[t]        = count[base + t];
    s[t + 1024] = count[base + t + 1024];
    __syncthreads();
    for (int off = 1; off < 2048; off <<= 1) {
        int a0 = (t >= off)        ? s[t - off]        : 0;
        int a1 = (t + 1024 >= off) ? s[t + 1024 - off] : 0;
        __syncthreads();
        s[t]        += a0;
        s[t + 1024] += a1;
        __syncthreads();
    }
    offs[base + t]        = s[t]        - count[base + t];
    offs[base + t + 1024] = s[t + 1024] - count[base + t + 1024];
    if (t == 0) blockSums[blockIdx.x] = s[2047];
}

// ================= K3b: scan the 128 block sums =================
__global__ void k_scan2(int* blockSums, int* offs) {
    if (threadIdx.x == 0) {
        int run = 0;
        for (int b = 0; b < 128; b++) { int v = blockSums[b]; blockSums[b] = run; run += v; }
        offs[N_NODES] = run;   // == E
    }
}

// ================= K3c: add block offsets, zero cursor, deg->dinv =================
__global__ void k_fixup(int* offs, int* count, float* deg, const int* blockSums) {
    int n = blockIdx.x * 256 + threadIdx.x;
    if (n >= N_NODES) return;
    offs[n] += blockSums[n >> 11];
    count[n] = 0;
    float d = deg[n];
    deg[n] = (d > 0.f) ? (1.0f / sqrtf(d)) : 0.f;   // in-place -> dinv
}

// ================= K4: scatter edges into CSR-by-dst =================
__global__ void k_scatter(const int* row, const int* col, const float* w, const float* dinv,
                          const int* offs, int* cursor, int* ssrc, float* scoef) {
    int e = blockIdx.x * 256 + threadIdx.x;
    if (e >= N_EDGES) return;
    int r = row[e], c = col[e];
    int pos = atomicAdd(&cursor[c], 1);
    int slot = offs[c] + pos;
    ssrc[slot]  = r;
    scoef[slot] = (dinv[r] * w[e]) * dinv[c];
}

// ================= K5: gather-aggregate (A_norm @ x), 32 lanes/node =================
__global__ void k_aggregate(const float* x, const float* dinv, const int* offs,
                            const int* ssrc, const float* scoef, float* agg) {
    int g = blockIdx.x * 256 + threadIdx.x;
    int node = g >> 5, d = g & 31;
    const float4* x4 = (const float4*)x;
    float4 acc = make_float4(0.f, 0.f, 0.f, 0.f);
    int s = offs[node], e = offs[node + 1];
    for (int j = s; j < e; j++) {
        int   src = ssrc[j];
        float cf  = scoef[j];
        float4 v = x4[(size_t)src * 32 + d];
        acc.x += cf * v.x; acc.y += cf * v.y; acc.z += cf * v.z; acc.w += cf * v.w;
    }
    float di = dinv[node];
    float cf = di * di;                 // self-loop: dinv*1*dinv
    float4 v = x4[(size_t)node * 32 + d];
    acc.x += cf * v.x; acc.y += cf * v.y; acc.z += cf * v.z; acc.w += cf * v.w;
    ((float4*)agg)[(size_t)node * 32 + d] = acc;
}

// ======== K6: in-place GEMM 128x128 tile, 8x8 micro-tile + bias + leaky + score ========
// sA XOR-swizzle: element (kk, r) stored at sA[kk*128 + (r ^ 8*(kk>>2))].
// Writes: bank = (r%32) ^ (8*(k4&3)) -> 2 lanes/bank (free). Reads: b128-aligned,
// 16-lane broadcast per address, 4 distinct bank groups -> conflict-free.
__global__ __launch_bounds__(256, 4) void k_gemm(float* hio, const float* Wg,
                                                 const float* bias, const float* pw,
                                                 const float* normPw, float* score) {
    __shared__ __align__(16) float sW[32 * 128];   // [kk][j]
    __shared__ __align__(16) float sA[32 * 128];   // [kk][r^swz]
    int tid = threadIdx.x;
    int cx = tid & 15;          // cols 8*cx .. 8*cx+7
    int ry = tid >> 4;          // rows 8*ry .. 8*ry+7
    int row0 = blockIdx.x * 128;

    float acc[8][8];
#pragma unroll
    for (int r = 0; r < 8; r++)
#pragma unroll
        for (int c = 0; c < 8; c++) acc[r][c] = 0.f;

    for (int k0 = 0; k0 < DIM; k0 += 32) {
#pragma unroll
        for (int i = 0; i < 4; i++) {           // W chunk: 32x128 floats = 1024 float4
            int f = tid + i * 256;
            int kk = f >> 5, j4 = f & 31;
            *(float4*)(sW + kk * 128 + j4 * 4) =
                *(const float4*)(Wg + (size_t)(k0 + kk) * 128 + j4 * 4);
        }
#pragma unroll
        for (int i = 0; i < 4; i++) {           // A chunk: 128 rows x 32 k = 1024 float4
            int f = tid + i * 256;
            int r = f >> 3, k4 = f & 7;
            float4 v = *(const float4*)(hio + (size_t)(row0 + r) * 128 + k0 + k4 * 4);
            int rs = r ^ (k4 * 8);
            sA[(k4 * 4 + 0) * 128 + rs] = v.x;
            sA[(k4 * 4 + 1) * 128 + rs] = v.y;
            sA[(k4 * 4 + 2) * 128 + rs] = v.z;
            sA[(k4 * 4 + 3) * 128 + rs] = v.w;
        }
        __syncthreads();
#pragma unroll
        for (int kk = 0; kk < 32; kk++) {
            const float* ap = sA + kk * 128 + ((8 * ry) ^ ((kk >> 2) * 8));
            float4 a0 = *(const float4*)(ap);
            float4 a1 = *(const float4*)(ap + 4);
            float4 w0 = *(const float4*)(sW + kk * 128 + 8 * cx);
            float4 w1 = *(const float4*)(sW + kk * 128 + 8 * cx + 4);
            float av[8] = {a0.x, a0.y, a0.z, a0.w, a1.x, a1.y, a1.z, a1.w};
            float wv[8] = {w0.x, w0.y, w0.z, w0.w, w1.x, w1.y, w1.z, w1.w};
#pragma unroll
            for (int r = 0; r < 8; r++)
#pragma unroll
                for (int c = 0; c < 8; c++) acc[r][c] += av[r] * wv[c];
        }
        __syncthreads();
    }

    float bv[8], pv[8];
#pragma unroll
    for (int c = 0; c < 8; c++) { bv[c] = bias[8 * cx + c]; pv[c] = pw[8 * cx + c]; }
    float nrm = normPw[0];

#pragma unroll
    for (int r = 0; r < 8; r++) {
        int row = row0 + 8 * ry + r;
        float hv[8];
        float p = 0.f;
#pragma unroll
        for (int c = 0; c < 8; c++) {
            float v = acc[r][c] + bv[c];
            v = (v >= 0.f) ? v : NEG_SLOPE * v;
            hv[c] = v;
            p += v * pv[c];
        }
        float4 o0 = make_float4(hv[0], hv[1], hv[2], hv[3]);
        float4 o1 = make_float4(hv[4], hv[5], hv[6], hv[7]);
        *(float4*)(hio + (size_t)row * 128 + 8 * cx)     = o0;
        *(float4*)(hio + (size_t)row * 128 + 8 * cx + 4) = o1;
#pragma unroll
        for (int m = 1; m < 16; m <<= 1) p += __shfl_xor(p, m, 64);
        if (cx == 0) score[row] = tanhf(p / nrm);
    }
}

// ================= K7: per-chunk LDS bitonic sort (128 blocks x 2048 keys) =================
__global__ __launch_bounds__(1024) void k_sortchunks(const float* score,
                                                     unsigned long long* keys) {
    __shared__ unsigned long long a[CHUNK];     // 16 KB
    int base = blockIdx.x * CHUNK;              // chunk-aligned within a graph
    int t = threadIdx.x;
#pragma unroll
    for (int i = 0; i < CHUNK / 1024; i++) {
        int p = t + i * 1024;
        int node = base + p;
        a[p] = pack_key(score[node], node & (N_PER - 1));
    }
    __syncthreads();
    for (int k = 2; k <= CHUNK; k <<= 1) {
        for (int j = k >> 1; j > 0; j >>= 1) {
#pragma unroll
            for (int q = 0; q < CHUNK / 2048; q++) {
                int tt = t + q * 1024;
                int i = ((tt & ~(j - 1)) << 1) | (tt & (j - 1));
                int l = i | j;
                bool asc = ((i & k) == 0);
                unsigned long long x = a[i], y = a[l];
                if ((x > y) == asc) { a[i] = y; a[l] = x; }
            }
            __syncthreads();
        }
    }
#pragma unroll
    for (int i = 0; i < CHUNK / 1024; i++) {
        int p = t + i * 1024;
        keys[base + p] = a[p];
    }
}

// ================= K8: rank via binary search over sorted chunks, fused extract =================
__global__ void k_rank(const float* score, const unsigned long long* keys,
                       int* perm, int* mapping, float* out) {
    int n = blockIdx.x * 256 + threadIdx.x;
    if (n >= N_NODES) return;
    int g = n >> 14;
    unsigned long long key = pack_key(score[n], n & (N_PER - 1));
    const unsigned long long* gb = keys + ((size_t)g << 14);
    int r = 0;
#pragma unroll
    for (int c = 0; c < N_PER / CHUNK; c++) {
        const unsigned long long* ch = gb + c * CHUNK;
        int lo = 0, hi = CHUNK;
        while (lo < hi) {
            int mid = (lo + hi) >> 1;
            if (ch[mid] < key) lo = mid + 1; else hi = mid;
        }
        r += lo;
    }
    if (r < KKEEP) {
        int i = (g << 13) + r;
        perm[i] = n;
        mapping[n] = i;
        out[X_BATCH + i] = (float)g;
    }
}

// ================= K10: gate kept rows =================
__global__ void k_gate(const float* h, const float* score, const int* perm, float* out) {
    int g = blockIdx.x * 256 + threadIdx.x;
    int i = g >> 5, d = g & 31;
    int node = perm[i];
    float sc = score[node];
    float4 v = ((const float4*)h)[(size_t)node * 32 + d];
    v.x *= sc; v.y *= sc; v.z *= sc; v.w *= sc;
    ((float4*)(out + X_OUT))[(size_t)i * 32 + d] = v;
}

// ================= K11: relabel edges =================
__global__ void k_edges(const int* row, const int* col, const float* w,
                        const int* mapping, float* out) {
    int e = blockIdx.x * 256 + threadIdx.x;
    if (e >= N_EDGES) return;
    int mr = mapping[row[e]], mc = mapping[col[e]];
    bool valid = (mr >= 0) && (mc >= 0);
    out[X_EI + e]           = valid ? (float)mr : 0.f;
    out[X_EI + N_EDGES + e] = valid ? (float)mc : 0.f;
    out[X_EW + e]           = valid ? w[e] : 0.f;
}

extern "C" void kernel_launch(void* const* d_in, const int* in_sizes, int n_in,
                              void* d_out, int out_size, void* d_ws, size_t ws_size,
                              hipStream_t stream) {
    const float* x     = (const float*)d_in[0];
    const int*   ei    = (const int*)d_in[1];
    const float* ew    = (const float*)d_in[2];
    const float* Wc    = (const float*)d_in[4];
    const float* bias  = (const float*)d_in[5];
    const float* pw    = (const float*)d_in[6];
    float* out = (float*)d_out;

    const int* rowp = ei;
    const int* colp = ei + N_EDGES;

    char* wsb = (char*)d_ws;
    float* agg     = (float*)(wsb);                          // N*128*4 = 134217728
    float* dinv    = (float*)(wsb + 134217728);              // N*4 (deg, then dinv)
    int*   count   = (int*)  (wsb + 135266304);              // N*4 (counts, then cursor)
    int*   offs    = (int*)  (wsb + 136314880);              // (N+1)*4 padded
    int*   ssrc    = (int*)  (wsb + 137363712);              // E*4
    float* scoef   = (float*)(wsb + 139460864);              // E*4
    float* score   = (float*)(wsb + 141557760);              // N*4
    unsigned long long* keys = (unsigned long long*)(wsb + 142606336);  // N*8
    int*   perm    = (int*)  (wsb + 144703488);              // B*K*4
    int*   mapping = (int*)  (wsb + 145227776);              // N*4
    int*   blockSums = (int*)(wsb + 146276352);              // 128*4 padded
    float* normPw  = (float*)(wsb + 146277376);              // 4

    k_init   <<<N_NODES / 256, 256, 0, stream>>>(dinv, count, mapping, pw, normPw);
    k_deg    <<<N_EDGES / 256, 256, 0, stream>>>(colp, ew, dinv, count);
    k_scan1  <<<128, 1024, 0, stream>>>(count, offs, blockSums);
    k_scan2  <<<1, 64, 0, stream>>>(blockSums, offs);
    k_fixup  <<<N_NODES / 256, 256, 0, stream>>>(offs, count, dinv, blockSums);
    k_scatter<<<N_EDGES / 256, 256, 0, stream>>>(rowp, colp, ew, dinv, offs, count, ssrc, scoef);
    k_aggregate<<<(N_NODES * 32) / 256, 256, 0, stream>>>(x, dinv, offs, ssrc, scoef, agg);
    k_gemm   <<<N_NODES / 128, 256, 0, stream>>>(agg, Wc, bias, pw, normPw, score);
    k_sortchunks<<<N_NODES / CHUNK, 1024, 0, stream>>>(score, keys);
    k_rank   <<<N_NODES / 256, 256, 0, stream>>>(score, keys, perm, mapping, out);
    k_gate   <<<(NB * KKEEP * 32) / 256, 256, 0, stream>>>(agg, score, perm, out);
    k_edges  <<<N_EDGES / 256, 256, 0, stream>>>(rowp, colp, ew, mapping, out);
}

// Round 4
// 551.226 us; speedup vs baseline: 1.1050x; 1.1050x over previous
//
#include <hip/hip_runtime.h>
#include <math.h>

#define N_NODES 262144
#define N_EDGES 524288
#define NB      16
#define N_PER   16384
#define KKEEP   8192
#define DIM     128
#define NEG_SLOPE 0.01f
#define CHUNK   2048        // sort chunk size (8 chunks per graph)

// ---- output layout (floats) ----
#define X_OUT   0                     // 131072*128 = 16777216
#define X_EI    16777216              // 2*E = 1048576
#define X_EW    17825792              // E   = 524288
#define X_BATCH 18350080              // B*K = 131072

__device__ __forceinline__ unsigned long long pack_key(float sc, int localIdx) {
    unsigned int u = __float_as_uint(sc);
    u = (u & 0x80000000u) ? ~u : (u | 0x80000000u);   // order-preserving map
    unsigned int inv = ~u;                            // descending score
    return ((unsigned long long)inv << 32) | (unsigned int)localIdx;
}

// ================= K1: init =================
__global__ void k_init(float* deg, int* count, int* mapping, const float* pw, float* normPw) {
    int n = blockIdx.x * 256 + threadIdx.x;
    if (n < N_NODES) { deg[n] = 1.0f; count[n] = 0; mapping[n] = -1; }
    if (n == 0) {
        float s = 0.f;
        for (int i = 0; i < DIM; i++) s += pw[i] * pw[i];
        normPw[0] = sqrtf(s);
    }
}

// ================= K2: degree + in-edge counts =================
__global__ void k_deg(const int* col, const float* w, float* deg, int* count) {
    int e = blockIdx.x * 256 + threadIdx.x;
    if (e >= N_EDGES) return;
    int c = col[e];
    atomicAdd(&deg[c], w[e]);
    atomicAdd(&count[c], 1);
}

// ================= K3a: per-block exclusive scan (2048/block) =================
__global__ void k_scan1(const int* count, int* offs, int* blockSums) {
    __shared__ int s[2048];
    int base = blockIdx.x * 2048;
    int t = threadIdx.x;  // 1024 threads
    s[t]        = count[base + t];
    s[t + 1024] = count[base + t + 1024];
    __syncthreads();
    for (int off = 1; off < 2048; off <<= 1) {
        int a0 = (t >= off)        ? s[t - off]        : 0;
        int a1 = (t + 1024 >= off) ? s[t + 1024 - off] : 0;
        __syncthreads();
        s[t]        += a0;
        s[t + 1024] += a1;
        __syncthreads();
    }
    offs[base + t]        = s[t]        - count[base + t];
    offs[base + t + 1024] = s[t + 1024] - count[base + t + 1024];
    if (t == 0) blockSums[blockIdx.x] = s[2047];
}

// ================= K3b: scan the 128 block sums =================
__global__ void k_scan2(int* blockSums, int* offs) {
    if (threadIdx.x == 0) {
        int run = 0;
        for (int b = 0; b < 128; b++) { int v = blockSums[b]; blockSums[b] = run; run += v; }
        offs[N_NODES] = run;   // == E
    }
}

// ================= K3c: add block offsets, zero cursor, deg->dinv =================
__global__ void k_fixup(int* offs, int* count, float* deg, const int* blockSums) {
    int n = blockIdx.x * 256 + threadIdx.x;
    if (n >= N_NODES) return;
    offs[n] += blockSums[n >> 11];
    count[n] = 0;
    float d = deg[n];
    deg[n] = (d > 0.f) ? (1.0f / sqrtf(d)) : 0.f;   // in-place -> dinv
}

// ================= K4: scatter edges into CSR-by-dst =================
__global__ void k_scatter(const int* row, const int* col, const float* w, const float* dinv,
                          const int* offs, int* cursor, int* ssrc, float* scoef) {
    int e = blockIdx.x * 256 + threadIdx.x;
    if (e >= N_EDGES) return;
    int r = row[e], c = col[e];
    int pos = atomicAdd(&cursor[c], 1);
    int slot = offs[c] + pos;
    ssrc[slot]  = r;
    scoef[slot] = (dinv[r] * w[e]) * dinv[c];
}

// ================= K5: gather-aggregate (A_norm @ x), 32 lanes/node =================
__global__ void k_aggregate(const float* x, const float* dinv, const int* offs,
                            const int* ssrc, const float* scoef, float* agg) {
    int g = blockIdx.x * 256 + threadIdx.x;
    int node = g >> 5, d = g & 31;
    const float4* x4 = (const float4*)x;
    float4 acc = make_float4(0.f, 0.f, 0.f, 0.f);
    int s = offs[node], e = offs[node + 1];
    for (int j = s; j < e; j++) {
        int   src = ssrc[j];
        float cf  = scoef[j];
        float4 v = x4[(size_t)src * 32 + d];
        acc.x += cf * v.x; acc.y += cf * v.y; acc.z += cf * v.z; acc.w += cf * v.w;
    }
    float di = dinv[node];
    float cf = di * di;                 // self-loop: dinv*1*dinv
    float4 v = x4[(size_t)node * 32 + d];
    acc.x += cf * v.x; acc.y += cf * v.y; acc.z += cf * v.z; acc.w += cf * v.w;
    ((float4*)agg)[(size_t)node * 32 + d] = acc;
}

// ======== K6: in-place GEMM 128x128 tile, 8x8 micro-tile + bias + leaky + score ========
// sA XOR-swizzle: element (kk, r) stored at sA[kk*128 + (r ^ 8*(kk>>2))].
// Writes: 2 lanes/bank (free). Reads: b128-aligned 16-lane broadcast, conflict-free.
// launch_bounds(256,2): VGPR cap 256 -> NO accumulator spill (R3's (256,4) capped
// at 128 and spilled acc[8][8] to scratch: +260MB HBM traffic, 42% VALU).
__global__ __launch_bounds__(256, 2) void k_gemm(float* hio, const float* Wg,
                                                 const float* bias, const float* pw,
                                                 const float* normPw, float* score) {
    __shared__ __align__(16) float sW[32 * 128];   // [kk][j]
    __shared__ __align__(16) float sA[32 * 128];   // [kk][r^swz]
    int tid = threadIdx.x;
    int cx = tid & 15;          // cols 8*cx .. 8*cx+7
    int ry = tid >> 4;          // rows 8*ry .. 8*ry+7
    int row0 = blockIdx.x * 128;

    float acc[8][8];
#pragma unroll
    for (int r = 0; r < 8; r++)
#pragma unroll
        for (int c = 0; c < 8; c++) acc[r][c] = 0.f;

    for (int k0 = 0; k0 < DIM; k0 += 32) {
#pragma unroll
        for (int i = 0; i < 4; i++) {           // W chunk: 32x128 floats = 1024 float4
            int f = tid + i * 256;
            int kk = f >> 5, j4 = f & 31;
            *(float4*)(sW + kk * 128 + j4 * 4) =
                *(const float4*)(Wg + (size_t)(k0 + kk) * 128 + j4 * 4);
        }
#pragma unroll
        for (int i = 0; i < 4; i++) {           // A chunk: 128 rows x 32 k = 1024 float4
            int f = tid + i * 256;
            int r = f >> 3, k4 = f & 7;
            float4 v = *(const float4*)(hio + (size_t)(row0 + r) * 128 + k0 + k4 * 4);
            int rs = r ^ (k4 * 8);
            sA[(k4 * 4 + 0) * 128 + rs] = v.x;
            sA[(k4 * 4 + 1) * 128 + rs] = v.y;
            sA[(k4 * 4 + 2) * 128 + rs] = v.z;
            sA[(k4 * 4 + 3) * 128 + rs] = v.w;
        }
        __syncthreads();
#pragma unroll
        for (int kk = 0; kk < 32; kk++) {
            const float* ap = sA + kk * 128 + ((8 * ry) ^ ((kk >> 2) * 8));
            float4 a0 = *(const float4*)(ap);
            float4 a1 = *(const float4*)(ap + 4);
            float4 w0 = *(const float4*)(sW + kk * 128 + 8 * cx);
            float4 w1 = *(const float4*)(sW + kk * 128 + 8 * cx + 4);
            float av[8] = {a0.x, a0.y, a0.z, a0.w, a1.x, a1.y, a1.z, a1.w};
            float wv[8] = {w0.x, w0.y, w0.z, w0.w, w1.x, w1.y, w1.z, w1.w};
#pragma unroll
            for (int r = 0; r < 8; r++)
#pragma unroll
                for (int c = 0; c < 8; c++) acc[r][c] += av[r] * wv[c];
        }
        __syncthreads();
    }

    float bv[8], pv[8];
#pragma unroll
    for (int c = 0; c < 8; c++) { bv[c] = bias[8 * cx + c]; pv[c] = pw[8 * cx + c]; }
    float nrm = normPw[0];

#pragma unroll
    for (int r = 0; r < 8; r++) {
        int row = row0 + 8 * ry + r;
        float hv[8];
        float p = 0.f;
#pragma unroll
        for (int c = 0; c < 8; c++) {
            float v = acc[r][c] + bv[c];
            v = (v >= 0.f) ? v : NEG_SLOPE * v;
            hv[c] = v;
            p += v * pv[c];
        }
        float4 o0 = make_float4(hv[0], hv[1], hv[2], hv[3]);
        float4 o1 = make_float4(hv[4], hv[5], hv[6], hv[7]);
        *(float4*)(hio + (size_t)row * 128 + 8 * cx)     = o0;
        *(float4*)(hio + (size_t)row * 128 + 8 * cx + 4) = o1;
#pragma unroll
        for (int m = 1; m < 16; m <<= 1) p += __shfl_xor(p, m, 64);
        if (cx == 0) score[row] = tanhf(p / nrm);
    }
}

// ================= K7: per-chunk LDS bitonic sort (128 blocks x 2048 keys) =================
__global__ __launch_bounds__(1024) void k_sortchunks(const float* score,
                                                     unsigned long long* keys) {
    __shared__ unsigned long long a[CHUNK];     // 16 KB
    int base = blockIdx.x * CHUNK;              // chunk-aligned within a graph
    int t = threadIdx.x;
#pragma unroll
    for (int i = 0; i < CHUNK / 1024; i++) {
        int p = t + i * 1024;
        int node = base + p;
        a[p] = pack_key(score[node], node & (N_PER - 1));
    }
    __syncthreads();
    for (int k = 2; k <= CHUNK; k <<= 1) {
        for (int j = k >> 1; j > 0; j >>= 1) {
#pragma unroll
            for (int q = 0; q < CHUNK / 2048; q++) {
                int tt = t + q * 1024;
                int i = ((tt & ~(j - 1)) << 1) | (tt & (j - 1));
                int l = i | j;
                bool asc = ((i & k) == 0);
                unsigned long long x = a[i], y = a[l];
                if ((x > y) == asc) { a[i] = y; a[l] = x; }
            }
            __syncthreads();
        }
    }
#pragma unroll
    for (int i = 0; i < CHUNK / 1024; i++) {
        int p = t + i * 1024;
        keys[base + p] = a[p];
    }
}

// ================= K8: rank via binary search over sorted chunks, fused extract =================
__global__ void k_rank(const float* score, const unsigned long long* keys,
                       int* perm, int* mapping, float* out) {
    int n = blockIdx.x * 256 + threadIdx.x;
    if (n >= N_NODES) return;
    int g = n >> 14;
    unsigned long long key = pack_key(score[n], n & (N_PER - 1));
    const unsigned long long* gb = keys + ((size_t)g << 14);
    int r = 0;
#pragma unroll
    for (int c = 0; c < N_PER / CHUNK; c++) {
        const unsigned long long* ch = gb + c * CHUNK;
        int lo = 0, hi = CHUNK;
        while (lo < hi) {
            int mid = (lo + hi) >> 1;
            if (ch[mid] < key) lo = mid + 1; else hi = mid;
        }
        r += lo;
    }
    if (r < KKEEP) {
        int i = (g << 13) + r;
        perm[i] = n;
        mapping[n] = i;
        out[X_BATCH + i] = (float)g;
    }
}

// ================= K10: gate kept rows =================
__global__ void k_gate(const float* h, const float* score, const int* perm, float* out) {
    int g = blockIdx.x * 256 + threadIdx.x;
    int i = g >> 5, d = g & 31;
    int node = perm[i];
    float sc = score[node];
    float4 v = ((const float4*)h)[(size_t)node * 32 + d];
    v.x *= sc; v.y *= sc; v.z *= sc; v.w *= sc;
    ((float4*)(out + X_OUT))[(size_t)i * 32 + d] = v;
}

// ================= K11: relabel edges =================
__global__ void k_edges(const int* row, const int* col, const float* w,
                        const int* mapping, float* out) {
    int e = blockIdx.x * 256 + threadIdx.x;
    if (e >= N_EDGES) return;
    int mr = mapping[row[e]], mc = mapping[col[e]];
    bool valid = (mr >= 0) && (mc >= 0);
    out[X_EI + e]           = valid ? (float)mr : 0.f;
    out[X_EI + N_EDGES + e] = valid ? (float)mc : 0.f;
    out[X_EW + e]           = valid ? w[e] : 0.f;
}

extern "C" void kernel_launch(void* const* d_in, const int* in_sizes, int n_in,
                              void* d_out, int out_size, void* d_ws, size_t ws_size,
                              hipStream_t stream) {
    const float* x     = (const float*)d_in[0];
    const int*   ei    = (const int*)d_in[1];
    const float* ew    = (const float*)d_in[2];
    const float* Wc    = (const float*)d_in[4];
    const float* bias  = (const float*)d_in[5];
    const float* pw    = (const float*)d_in[6];
    float* out = (float*)d_out;

    const int* rowp = ei;
    const int* colp = ei + N_EDGES;

    char* wsb = (char*)d_ws;
    float* agg     = (float*)(wsb);                          // N*128*4 = 134217728
    float* dinv    = (float*)(wsb + 134217728);              // N*4 (deg, then dinv)
    int*   count   = (int*)  (wsb + 135266304);              // N*4 (counts, then cursor)
    int*   offs    = (int*)  (wsb + 136314880);              // (N+1)*4 padded
    int*   ssrc    = (int*)  (wsb + 137363712);              // E*4
    float* scoef   = (float*)(wsb + 139460864);              // E*4
    float* score   = (float*)(wsb + 141557760);              // N*4
    unsigned long long* keys = (unsigned long long*)(wsb + 142606336);  // N*8
    int*   perm    = (int*)  (wsb + 144703488);              // B*K*4
    int*   mapping = (int*)  (wsb + 145227776);              // N*4
    int*   blockSums = (int*)(wsb + 146276352);              // 128*4 padded
    float* normPw  = (float*)(wsb + 146277376);              // 4

    k_init   <<<N_NODES / 256, 256, 0, stream>>>(dinv, count, mapping, pw, normPw);
    k_deg    <<<N_EDGES / 256, 256, 0, stream>>>(colp, ew, dinv, count);
    k_scan1  <<<128, 1024, 0, stream>>>(count, offs, blockSums);
    k_scan2  <<<1, 64, 0, stream>>>(blockSums, offs);
    k_fixup  <<<N_NODES / 256, 256, 0, stream>>>(offs, count, dinv, blockSums);
    k_scatter<<<N_EDGES / 256, 256, 0, stream>>>(rowp, colp, ew, dinv, offs, count, ssrc, scoef);
    k_aggregate<<<(N_NODES * 32) / 256, 256, 0, stream>>>(x, dinv, offs, ssrc, scoef, agg);
    k_gemm   <<<N_NODES / 128, 256, 0, stream>>>(agg, Wc, bias, pw, normPw, score);
    k_sortchunks<<<N_NODES / CHUNK, 1024, 0, stream>>>(score, keys);
    k_rank   <<<N_NODES / 256, 256, 0, stream>>>(score, keys, perm, mapping, out);
    k_gate   <<<(NB * KKEEP * 32) / 256, 256, 0, stream>>>(agg, score, perm, out);
    k_edges  <<<N_EDGES / 256, 256, 0, stream>>>(rowp, colp, ew, mapping, out);
}